// Round 3
// baseline (6351.828 us; speedup 1.0000x reference)
//
#include <hip/hip_runtime.h>

#define B_DIM 8
#define CIN   32
#define COUT  64
#define KCH   4
#define F_DIM 256   // B_DIM*CIN
#define CHUNK 64    // f's per chunk (= 2 batches); 4 chunks
#define NCHUNK 4

// ---------------------------------------------------------------- utilities

__global__ __launch_bounds__(256) void zero_kernel(int* p, int n) {
    int i = blockIdx.x * 256 + threadIdx.x;
    if (i < n) p[i] = 0;
}

__global__ __launch_bounds__(256) void hist_kernel(const int* __restrict__ L_row,
                                                   int* __restrict__ cnt, int nnz) {
    int i = blockIdx.x * 256 + threadIdx.x;
    if (i < nnz) atomicAdd(&cnt[L_row[i]], 1);
}

// single-block exclusive scan, 8 elements/thread (13 iterations for M=100k).
__global__ __launch_bounds__(1024) void scan_kernel(int* __restrict__ cursor,
                                                    int* __restrict__ row_ptr, int M) {
    __shared__ int wsum[16];
    __shared__ int sbase_s;
    int tid = threadIdx.x, lane = tid & 63, wid = tid >> 6;
    if (tid == 0) sbase_s = 0;
    __syncthreads();
    int nchunk = (M + 8191) / 8192;
    for (int ch = 0; ch < nchunk; ch++) {
        int i0 = ch * 8192 + tid * 8;
        int v[8];
        if (i0 + 8 <= M) {
            int4 a = *(const int4*)&cursor[i0];
            int4 b = *(const int4*)&cursor[i0 + 4];
            v[0]=a.x; v[1]=a.y; v[2]=a.z; v[3]=a.w;
            v[4]=b.x; v[5]=b.y; v[6]=b.z; v[7]=b.w;
        } else {
            #pragma unroll
            for (int t = 0; t < 8; t++) v[t] = (i0 + t < M) ? cursor[i0 + t] : 0;
        }
        int s = 0;
        #pragma unroll
        for (int t = 0; t < 8; t++) { int tmp = v[t]; v[t] = s; s += tmp; }
        int sc = s;
        #pragma unroll
        for (int d = 1; d < 64; d <<= 1) {
            int t = __shfl_up(sc, d);
            if (lane >= d) sc += t;
        }
        if (lane == 63) wsum[wid] = sc;
        __syncthreads();
        if (wid == 0) {
            int w = (lane < 16) ? wsum[lane] : 0;
            #pragma unroll
            for (int d = 1; d < 16; d <<= 1) {
                int t = __shfl_up(w, d);
                if (lane >= d) w += t;
            }
            if (lane < 16) wsum[lane] = w;
        }
        __syncthreads();
        int base = sbase_s + ((wid > 0) ? wsum[wid - 1] : 0) + (sc - s);
        #pragma unroll
        for (int t = 0; t < 8; t++) {
            int idx = i0 + t;
            if (idx < M) { int e = base + v[t]; row_ptr[idx] = e; cursor[idx] = e; }
        }
        __syncthreads();
        if (tid == 0) sbase_s += wsum[15];
        __syncthreads();
    }
    if (tid == 0) row_ptr[M] = sbase_s;
}

// pack (col, val) int2 pairs in CSR order
__global__ __launch_bounds__(256) void scatter_kernel(
        const int* __restrict__ L_row, const int* __restrict__ L_col,
        const float* __restrict__ L_val,
        int* __restrict__ cursor, int2* __restrict__ cv, int nnz) {
    int i = blockIdx.x * 256 + threadIdx.x;
    if (i < nnz) {
        int r = L_row[i];
        int p = atomicAdd(&cursor[r], 1);
        int2 e;
        e.x = L_col[i];
        e.y = __float_as_int(L_val[i]);
        cv[p] = e;
    }
}

// theta (COUT,CIN,K) -> th_t[(k*CIN+i)*COUT + o]
__global__ __launch_bounds__(256) void th_prep_kernel(const float* __restrict__ theta,
                                                      float* __restrict__ th_t) {
    int idx = blockIdx.x * 256 + threadIdx.x;
    if (idx < KCH * CIN * COUT) {
        int o = idx & 63;
        int rest = idx >> 6;
        int i = rest & 31;
        int k = rest >> 5;
        th_t[idx] = theta[(o * CIN + i) * KCH + k];
    }
}

// x rows [f0, f0+64) -> X0c (M, 64): 64x64 LDS tile transpose
__global__ __launch_bounds__(256) void transpose_kernel(const float* __restrict__ x,
                                                        float* __restrict__ X0c,
                                                        int M, int f0) {
    __shared__ float tile[64][65];
    int tid = threadIdx.x;
    int ml = tid & 63;
    int fl0 = tid >> 6;               // 0..3
    int m0 = blockIdx.x * 64;
    #pragma unroll 4
    for (int ff = fl0; ff < 64; ff += 4) {
        int m = m0 + ml;
        tile[ff][ml] = (m < M) ? x[(size_t)(f0 + ff) * M + m] : 0.f;
    }
    __syncthreads();
    int fl = tid & 63;
    #pragma unroll 4
    for (int mm = fl0; mm < 64; mm += 4) {
        int m = m0 + mm;
        if (m < M) X0c[m * CHUNK + fl] = tile[fl][mm];
    }
}

// ---------------------------------------------------------------- SpMM core
// One wave gathers one CSR row over a 64-float chunk: lane owns 1 float.
// acc = sum_e val[e] * Xi[col[e]*64 + lane]; 4-deep software pipeline.
__device__ __forceinline__ float gather_row_c(const int2* __restrict__ cv,
                                              int start, int end,
                                              const float* __restrict__ Xi,
                                              int lane) {
    float acc = 0.f;
    for (int base = start; base < end; base += 64) {
        int e = base + lane;
        int cl = 0; float vl = 0.f;
        if (e < end) { int2 p = cv[e]; cl = p.x; vl = __int_as_float(p.y); }
        int cnt = min(64, end - base);
        int c0 = __shfl(cl, 0), c1 = __shfl(cl, 1), c2 = __shfl(cl, 2), c3 = __shfl(cl, 3);
        float h0 = Xi[c0 * CHUNK + lane];
        float h1 = Xi[c1 * CHUNK + lane];
        float h2 = Xi[c2 * CHUNK + lane];
        float h3 = Xi[c3 * CHUNK + lane];
        for (int j = 0; j < cnt; j += 4) {
            float g0 = h0, g1 = h1, g2 = h2, g3 = h3;
            int jn = j + 4;
            if (jn < cnt) {
                int d0 = __shfl(cl, jn), d1 = __shfl(cl, jn + 1);
                int d2 = __shfl(cl, jn + 2), d3 = __shfl(cl, jn + 3);
                h0 = Xi[d0 * CHUNK + lane];
                h1 = Xi[d1 * CHUNK + lane];
                h2 = Xi[d2 * CHUNK + lane];
                h3 = Xi[d3 * CHUNK + lane];
            }
            float v0 = __shfl(vl, j),     v1 = __shfl(vl, j + 1);
            float v2 = __shfl(vl, j + 2), v3 = __shfl(vl, j + 3);
            acc += v0 * g0; acc += v1 * g1; acc += v2 * g2; acc += v3 * g3;
        }
    }
    return acc;
}

// MODE 1: Xout = L*Xin ; MODE 2: Xout = 2*L*Xin - Xprev   (per 64-f chunk)
template <int MODE>
__global__ __launch_bounds__(256) void spmm_kernel(
        const int* __restrict__ row_ptr, const int2* __restrict__ cv,
        const float* __restrict__ Xin, const float* __restrict__ Xprev,
        float* __restrict__ Xout, int M) {
    int lane = threadIdx.x & 63, wid = threadIdx.x >> 6;
    int m = blockIdx.x * 4 + wid;
    if (m >= M) return;
    int start = row_ptr[m], end = row_ptr[m + 1];
    float acc = gather_row_c(cv, start, end, Xin, lane);
    float outv = (MODE == 1) ? acc : 2.f * acc - Xprev[m * CHUNK + lane];
    Xout[m * CHUNK + lane] = outv;
}

// -------------------------------------------- fused SpMM3 + einsum + bias
// Per chunk (2 batches). Block = 256 threads, 16 rows.
// Phase 1: 4 waves gather X3 = 2*L*X2 - X1 rows into x_lds.
// Phase 2: einsum k-order {3,0,1,2}, reusing x_lds for the staged X0/X1/X2.
__device__ __forceinline__ void accum_k(const float* __restrict__ thk,
                                        const float* __restrict__ xr,
                                        int og, float acc[8]) {
    #pragma unroll
    for (int i4 = 0; i4 < 8; i4++) {
        float4 xa = *(const float4*)&xr[i4 * 4];
        float xs[4] = {xa.x, xa.y, xa.z, xa.w};
        #pragma unroll
        for (int c = 0; c < 4; c++) {
            const float* tp = &thk[(i4 * 4 + c) * COUT + og * 8];
            float4 t0 = *(const float4*)tp;
            float4 t1 = *(const float4*)(tp + 4);
            float a = xs[c];
            acc[0] += a * t0.x; acc[1] += a * t0.y; acc[2] += a * t0.z; acc[3] += a * t0.w;
            acc[4] += a * t1.x; acc[5] += a * t1.y; acc[6] += a * t1.z; acc[7] += a * t1.w;
        }
    }
}

__global__ __launch_bounds__(256) void spmm3_einsum_kernel(
        const int* __restrict__ row_ptr, const int2* __restrict__ cv,
        const float* __restrict__ X0, const float* __restrict__ X1,
        const float* __restrict__ X2,
        const float* __restrict__ th_t, const float* __restrict__ bias,
        float* __restrict__ y, int M, int bbase) {
    __shared__ __align__(16) float th_lds[KCH * CIN * COUT];  // 32 KB
    __shared__ __align__(16) float x_lds[16][68];             // 4.25 KB (reused)

    int tid = threadIdx.x;
    int lane = tid & 63, wid = tid >> 6;

    #pragma unroll
    for (int i = tid * 4; i < KCH * CIN * COUT; i += 1024)
        *(float4*)&th_lds[i] = *(const float4*)&th_t[i];

    // ---- phase 1: X3 rows into x_lds
    #pragma unroll
    for (int rr = 0; rr < 4; rr++) {
        int r = wid + rr * 4;
        int m = blockIdx.x * 16 + r;
        if (m < M) {
            int start = row_ptr[m], end = row_ptr[m + 1];
            float acc = gather_row_c(cv, start, end, X2, lane);
            x_lds[r][lane] = 2.f * acc - X1[m * CHUNK + lane];
        }
    }
    __syncthreads();

    // ---- phase 2: einsum. r=rows(16), og=o-group(8), bsel=batch-in-chunk(2)
    int r = tid & 15, h = tid >> 4;
    int og = h & 7, bsel = h >> 3;
    int m = blockIdx.x * 16 + r;

    float acc[8] = {0.f, 0.f, 0.f, 0.f, 0.f, 0.f, 0.f, 0.f};

    // k = 3 (x_lds currently holds X3)
    accum_k(&th_lds[3 * CIN * COUT], &x_lds[r][bsel * 32], og, acc);

    #pragma unroll
    for (int k = 0; k < 3; k++) {
        const float* Xs = (k == 0) ? X0 : (k == 1) ? X1 : X2;
        __syncthreads();                      // all reads of previous contents done
        int rr2 = tid >> 4, ff = (tid & 15) * 4;
        int mm = blockIdx.x * 16 + rr2;
        float4 v = {0.f, 0.f, 0.f, 0.f};
        if (mm < M) v = *(const float4*)&Xs[mm * CHUNK + ff];
        *(float4*)&x_lds[rr2][ff] = v;
        __syncthreads();
        accum_k(&th_lds[k * CIN * COUT], &x_lds[r][bsel * 32], og, acc);
    }

    if (m < M) {
        int b = bbase + bsel;
        #pragma unroll
        for (int oo = 0; oo < 8; oo++) {
            int o = og * 8 + oo;
            y[(b * COUT + o) * M + m] = acc[oo] + bias[o];
        }
    }
}

// ---------------------------------------------------------------- launcher

extern "C" void kernel_launch(void* const* d_in, const int* in_sizes, int n_in,
                              void* d_out, int out_size, void* d_ws, size_t ws_size,
                              hipStream_t stream) {
    const float* x     = (const float*)d_in[0];
    const int*   L_row = (const int*)d_in[1];
    const int*   L_col = (const int*)d_in[2];
    const float* L_val = (const float*)d_in[3];
    const float* theta = (const float*)d_in[4];
    const float* bias  = (const float*)d_in[5];
    float* y = (float*)d_out;

    int M   = in_sizes[0] / F_DIM;   // 100000
    int NNZ = in_sizes[1];           // 1600000
    int Mpad = (M + 4 + 3) & ~3;     // row_ptr region padded to 16B multiple

    // workspace layout (chunk buffers reused across 4 sequential chunks)
    size_t MC = (size_t)M * CHUNK;
    float* X0      = (float*)d_ws;
    float* X1      = X0 + MC;
    float* X2      = X1 + MC;
    float* th_t    = X2 + MC;                       // 8192 floats
    int*   row_ptr = (int*)(th_t + KCH * CIN * COUT);
    int*   cursor  = row_ptr + Mpad;
    int2*  cv      = (int2*)(cursor + ((M + 3) & ~3));

    // CSR build (once)
    zero_kernel<<<(M + 255) / 256, 256, 0, stream>>>(cursor, M);
    hist_kernel<<<(NNZ + 255) / 256, 256, 0, stream>>>(L_row, cursor, NNZ);
    scan_kernel<<<1, 1024, 0, stream>>>(cursor, row_ptr, M);
    scatter_kernel<<<(NNZ + 255) / 256, 256, 0, stream>>>(L_row, L_col, L_val,
                                                          cursor, cv, NNZ);
    th_prep_kernel<<<(KCH * CIN * COUT + 255) / 256, 256, 0, stream>>>(theta, th_t);

    // 4 sequential chunks of 64 f's (2 batches each) — per-chunk working set
    // (X0+X1+X2 = 77 MB + edges 13 MB + y chunk 51 MB) stays L3-resident.
    for (int c = 0; c < NCHUNK; c++) {
        transpose_kernel<<<(M + 63) / 64, 256, 0, stream>>>(x, X0, M, CHUNK * c);
        spmm_kernel<1><<<(M + 3) / 4, 256, 0, stream>>>(row_ptr, cv, X0, nullptr, X1, M);
        spmm_kernel<2><<<(M + 3) / 4, 256, 0, stream>>>(row_ptr, cv, X1, X0, X2, M);
        spmm3_einsum_kernel<<<(M + 15) / 16, 256, 0, stream>>>(row_ptr, cv, X0, X1, X2,
                                                               th_t, bias, y, M, 2 * c);
    }
}

// Round 4
// 1364.195 us; speedup vs baseline: 4.6561x; 4.6561x over previous
//
#include <hip/hip_runtime.h>

#define B_DIM 8
#define CIN   32
#define COUT  64
#define KCH   4
#define F_DIM 256   // B_DIM*CIN
#define CHUNK 64    // f's per chunk (= 2 batches); 4 chunks
#define NCHUNK 4
#define MB    16    // rows per einsum block

// ---------------------------------------------------------------- utilities

__global__ __launch_bounds__(256) void zero_kernel(int* p, int n) {
    int i = blockIdx.x * 256 + threadIdx.x;
    if (i < n) p[i] = 0;
}

__global__ __launch_bounds__(256) void hist_kernel(const int* __restrict__ L_row,
                                                   int* __restrict__ cnt, int nnz) {
    int i = blockIdx.x * 256 + threadIdx.x;
    if (i < nnz) atomicAdd(&cnt[L_row[i]], 1);
}

// single-block exclusive scan, 8 elements/thread.
__global__ __launch_bounds__(1024) void scan_kernel(int* __restrict__ cursor,
                                                    int* __restrict__ row_ptr, int M) {
    __shared__ int wsum[16];
    __shared__ int sbase_s;
    int tid = threadIdx.x, lane = tid & 63, wid = tid >> 6;
    if (tid == 0) sbase_s = 0;
    __syncthreads();
    int nchunk = (M + 8191) / 8192;
    for (int ch = 0; ch < nchunk; ch++) {
        int i0 = ch * 8192 + tid * 8;
        int v[8];
        if (i0 + 8 <= M) {
            int4 a = *(const int4*)&cursor[i0];
            int4 b = *(const int4*)&cursor[i0 + 4];
            v[0]=a.x; v[1]=a.y; v[2]=a.z; v[3]=a.w;
            v[4]=b.x; v[5]=b.y; v[6]=b.z; v[7]=b.w;
        } else {
            #pragma unroll
            for (int t = 0; t < 8; t++) v[t] = (i0 + t < M) ? cursor[i0 + t] : 0;
        }
        int s = 0;
        #pragma unroll
        for (int t = 0; t < 8; t++) { int tmp = v[t]; v[t] = s; s += tmp; }
        int sc = s;
        #pragma unroll
        for (int d = 1; d < 64; d <<= 1) {
            int t = __shfl_up(sc, d);
            if (lane >= d) sc += t;
        }
        if (lane == 63) wsum[wid] = sc;
        __syncthreads();
        if (wid == 0) {
            int w = (lane < 16) ? wsum[lane] : 0;
            #pragma unroll
            for (int d = 1; d < 16; d <<= 1) {
                int t = __shfl_up(w, d);
                if (lane >= d) w += t;
            }
            if (lane < 16) wsum[lane] = w;
        }
        __syncthreads();
        int base = sbase_s + ((wid > 0) ? wsum[wid - 1] : 0) + (sc - s);
        #pragma unroll
        for (int t = 0; t < 8; t++) {
            int idx = i0 + t;
            if (idx < M) { int e = base + v[t]; row_ptr[idx] = e; cursor[idx] = e; }
        }
        __syncthreads();
        if (tid == 0) sbase_s += wsum[15];
        __syncthreads();
    }
    if (tid == 0) row_ptr[M] = sbase_s;
}

// pack (col, val) int2 pairs in CSR order
__global__ __launch_bounds__(256) void scatter_kernel(
        const int* __restrict__ L_row, const int* __restrict__ L_col,
        const float* __restrict__ L_val,
        int* __restrict__ cursor, int2* __restrict__ cv, int nnz) {
    int i = blockIdx.x * 256 + threadIdx.x;
    if (i < nnz) {
        int r = L_row[i];
        int p = atomicAdd(&cursor[r], 1);
        int2 e;
        e.x = L_col[i];
        e.y = __float_as_int(L_val[i]);
        cv[p] = e;
    }
}

// theta (COUT,CIN,K) -> th_t[(k*CIN+i)*COUT + o]
__global__ __launch_bounds__(256) void th_prep_kernel(const float* __restrict__ theta,
                                                      float* __restrict__ th_t) {
    int idx = blockIdx.x * 256 + threadIdx.x;
    if (idx < KCH * CIN * COUT) {
        int o = idx & 63;
        int rest = idx >> 6;
        int i = rest & 31;
        int k = rest >> 5;
        th_t[idx] = theta[(o * CIN + i) * KCH + k];
    }
}

// x rows [f0, f0+64) -> X0c (M, 64): 64x64 LDS tile transpose
__global__ __launch_bounds__(256) void transpose_kernel(const float* __restrict__ x,
                                                        float* __restrict__ X0c,
                                                        int M, int f0) {
    __shared__ float tile[64][65];
    int tid = threadIdx.x;
    int ml = tid & 63;
    int fl0 = tid >> 6;               // 0..3
    int m0 = blockIdx.x * 64;
    #pragma unroll 4
    for (int ff = fl0; ff < 64; ff += 4) {
        int m = m0 + ml;
        tile[ff][ml] = (m < M) ? x[(size_t)(f0 + ff) * M + m] : 0.f;
    }
    __syncthreads();
    int fl = tid & 63;
    #pragma unroll 4
    for (int mm = fl0; mm < 64; mm += 4) {
        int m = m0 + mm;
        if (m < M) X0c[m * CHUNK + fl] = tile[fl][mm];
    }
}

// ---------------------------------------------------------------- SpMM core
// One wave gathers one CSR row over a 64-float chunk: lane owns 1 float.
// acc = sum_e val[e] * Xi[col[e]*64 + lane]; 4-deep software pipeline.
__device__ __forceinline__ float gather_row_c(const int2* __restrict__ cv,
                                              int start, int end,
                                              const float* __restrict__ Xi,
                                              int lane) {
    float acc = 0.f;
    for (int base = start; base < end; base += 64) {
        int e = base + lane;
        int cl = 0; float vl = 0.f;
        if (e < end) { int2 p = cv[e]; cl = p.x; vl = __int_as_float(p.y); }
        int cnt = min(64, end - base);
        int c0 = __shfl(cl, 0), c1 = __shfl(cl, 1), c2 = __shfl(cl, 2), c3 = __shfl(cl, 3);
        float h0 = Xi[c0 * CHUNK + lane];
        float h1 = Xi[c1 * CHUNK + lane];
        float h2 = Xi[c2 * CHUNK + lane];
        float h3 = Xi[c3 * CHUNK + lane];
        for (int j = 0; j < cnt; j += 4) {
            float g0 = h0, g1 = h1, g2 = h2, g3 = h3;
            int jn = j + 4;
            if (jn < cnt) {
                int d0 = __shfl(cl, jn), d1 = __shfl(cl, jn + 1);
                int d2 = __shfl(cl, jn + 2), d3 = __shfl(cl, jn + 3);
                h0 = Xi[d0 * CHUNK + lane];
                h1 = Xi[d1 * CHUNK + lane];
                h2 = Xi[d2 * CHUNK + lane];
                h3 = Xi[d3 * CHUNK + lane];
            }
            float v0 = __shfl(vl, j),     v1 = __shfl(vl, j + 1);
            float v2 = __shfl(vl, j + 2), v3 = __shfl(vl, j + 3);
            acc += v0 * g0; acc += v1 * g1; acc += v2 * g2; acc += v3 * g3;
        }
    }
    return acc;
}

// MODE 1: Xout = L*Xin ; MODE 2: Xout = 2*L*Xin - Xprev   (per 64-f chunk)
template <int MODE>
__global__ __launch_bounds__(256) void spmm_kernel(
        const int* __restrict__ row_ptr, const int2* __restrict__ cv,
        const float* __restrict__ Xin, const float* __restrict__ Xprev,
        float* __restrict__ Xout, int M) {
    int lane = threadIdx.x & 63, wid = threadIdx.x >> 6;
    int m = blockIdx.x * 4 + wid;
    if (m >= M) return;
    int start = row_ptr[m], end = row_ptr[m + 1];
    float acc = gather_row_c(cv, start, end, Xin, lane);
    float outv = (MODE == 1) ? acc : 2.f * acc - Xprev[m * CHUNK + lane];
    Xout[m * CHUNK + lane] = outv;
}

// ---------------------------------------------------------------- einsum
// Per chunk (2 batches): y[b,o,m] = bias[o] + sum_k sum_i th[k][i][o]*Xk[m][bsel*32+i]
// Block = 256 threads, MB=16 rows. Thread: r=tid&15 (row), og=(tid>>4)&7, bsel=tid>>7.
__device__ __forceinline__ void accum_k(const float* __restrict__ thk,
                                        const float* __restrict__ xr,
                                        int og, float acc[8]) {
    #pragma unroll
    for (int i4 = 0; i4 < 8; i4++) {
        float4 xa = *(const float4*)&xr[i4 * 4];
        float xs[4] = {xa.x, xa.y, xa.z, xa.w};
        #pragma unroll
        for (int c = 0; c < 4; c++) {
            const float* tp = &thk[(i4 * 4 + c) * COUT + og * 8];
            float4 t0 = *(const float4*)tp;
            float4 t1 = *(const float4*)(tp + 4);
            float a = xs[c];
            acc[0] += a * t0.x; acc[1] += a * t0.y; acc[2] += a * t0.z; acc[3] += a * t0.w;
            acc[4] += a * t1.x; acc[5] += a * t1.y; acc[6] += a * t1.z; acc[7] += a * t1.w;
        }
    }
}

__global__ __launch_bounds__(256) void einsum_kernel(
        const float* __restrict__ X0, const float* __restrict__ X1,
        const float* __restrict__ X2, const float* __restrict__ X3,
        const float* __restrict__ th_t, const float* __restrict__ bias,
        float* __restrict__ y, int M, int bbase) {
    __shared__ __align__(16) float th_lds[KCH * CIN * COUT];   // 32 KB
    __shared__ __align__(16) float x_lds[KCH][MB][68];         // 17.4 KB

    int tid = threadIdx.x;
    #pragma unroll
    for (int i = tid * 4; i < KCH * CIN * COUT; i += 1024)
        *(float4*)&th_lds[i] = *(const float4*)&th_t[i];

    // stage MB rows for all 4 k's (coalesced 256B row reads)
    int rr = tid >> 4, ff = (tid & 15) * 4;
    int mm = blockIdx.x * MB + rr;
    #pragma unroll
    for (int k = 0; k < KCH; k++) {
        const float* Xs = (k == 0) ? X0 : (k == 1) ? X1 : (k == 2) ? X2 : X3;
        float4 v = {0.f, 0.f, 0.f, 0.f};
        if (mm < M) v = *(const float4*)&Xs[mm * CHUNK + ff];
        *(float4*)&x_lds[k][rr][ff] = v;
    }
    __syncthreads();

    int r = tid & 15, h = tid >> 4;
    int og = h & 7, bsel = h >> 3;
    int m = blockIdx.x * MB + r;

    float acc[8] = {0.f, 0.f, 0.f, 0.f, 0.f, 0.f, 0.f, 0.f};
    #pragma unroll
    for (int k = 0; k < KCH; k++)
        accum_k(&th_lds[k * CIN * COUT], &x_lds[k][r][bsel * 32], og, acc);

    if (m < M) {
        int b = bbase + bsel;
        #pragma unroll
        for (int oo = 0; oo < 8; oo++) {
            int o = og * 8 + oo;
            y[(b * COUT + o) * M + m] = acc[oo] + bias[o];
        }
    }
}

// ---------------------------------------------------------------- launcher

extern "C" void kernel_launch(void* const* d_in, const int* in_sizes, int n_in,
                              void* d_out, int out_size, void* d_ws, size_t ws_size,
                              hipStream_t stream) {
    const float* x     = (const float*)d_in[0];
    const int*   L_row = (const int*)d_in[1];
    const int*   L_col = (const int*)d_in[2];
    const float* L_val = (const float*)d_in[3];
    const float* theta = (const float*)d_in[4];
    const float* bias  = (const float*)d_in[5];
    float* y = (float*)d_out;

    int M   = in_sizes[0] / F_DIM;   // 100000
    int NNZ = in_sizes[1];           // 1600000
    int Mpad = (M + 4 + 3) & ~3;     // row_ptr region padded to 16B multiple

    // workspace layout (chunk buffers reused across 4 sequential chunks)
    size_t MC = (size_t)M * CHUNK;
    float* X0      = (float*)d_ws;
    float* X1      = X0 + MC;
    float* X2      = X1 + MC;
    float* X3      = X2 + MC;
    float* th_t    = X3 + MC;                       // 8192 floats
    int*   row_ptr = (int*)(th_t + KCH * CIN * COUT);
    int*   cursor  = row_ptr + Mpad;
    int2*  cv      = (int2*)(cursor + ((M + 3) & ~3));

    // CSR build (once)
    zero_kernel<<<(M + 255) / 256, 256, 0, stream>>>(cursor, M);
    hist_kernel<<<(NNZ + 255) / 256, 256, 0, stream>>>(L_row, cursor, NNZ);
    scan_kernel<<<1, 1024, 0, stream>>>(cursor, row_ptr, M);
    scatter_kernel<<<(NNZ + 255) / 256, 256, 0, stream>>>(L_row, L_col, L_val,
                                                          cursor, cv, NNZ);
    th_prep_kernel<<<(KCH * CIN * COUT + 255) / 256, 256, 0, stream>>>(theta, th_t);

    // 4 sequential chunks of 64 f's (2 batches each); per-chunk X working set
    // (4 x 25.6 MB) + edges (12.8 MB) + y chunk (51 MB) stays L3-resident.
    for (int c = 0; c < NCHUNK; c++) {
        transpose_kernel<<<(M + 63) / 64, 256, 0, stream>>>(x, X0, M, CHUNK * c);
        spmm_kernel<1><<<(M + 3) / 4, 256, 0, stream>>>(row_ptr, cv, X0, nullptr, X1, M);
        spmm_kernel<2><<<(M + 3) / 4, 256, 0, stream>>>(row_ptr, cv, X1, X0, X2, M);
        spmm_kernel<2><<<(M + 3) / 4, 256, 0, stream>>>(row_ptr, cv, X2, X1, X3, M);
        einsum_kernel<<<(M + MB - 1) / MB, 256, 0, stream>>>(X0, X1, X2, X3,
                                                             th_t, bias, y, M, 2 * c);
    }
}